// Round 4
// baseline (270.955 us; speedup 1.0000x reference)
//
#include <hip/hip_runtime.h>

#define N 8192
#define FI 256
#define FO 128

typedef short bf16x8 __attribute__((ext_vector_type(8)));
typedef float f32x4 __attribute__((ext_vector_type(4)));
typedef unsigned short u16x4 __attribute__((ext_vector_type(4)));
typedef unsigned long long u64;
typedef u64 u64x2 __attribute__((ext_vector_type(2)));

static __device__ __forceinline__ unsigned short f2bf(float x) {
  unsigned int u = __builtin_bit_cast(unsigned int, x);
  u = (u + 0x7fffu + ((u >> 16) & 1u)) >> 16;
  return (unsigned short)u;
}
static __device__ __forceinline__ float lrelu(float x) {
  return fmaxf(x, 0.01f * x);
}
// Barrier that waits only on LDS ops — attn stores / h_t prefetches stay in flight (T4).
static __device__ __forceinline__ void barrier_lds() {
  asm volatile("s_waitcnt lgkmcnt(0)" ::: "memory");
  __builtin_amdgcn_s_barrier();
  asm volatile("" ::: "memory");
}

// Kernel A: h = x@W (f32 accum); write h transposed bf16 h_t[FO][N]; ha1 = h@a1, ha2 = h@a2.
__global__ __launch_bounds__(256) void k_prep(
    const float* __restrict__ x, const float* __restrict__ W, const float* __restrict__ a,
    unsigned short* __restrict__ h_t, float* __restrict__ ha1, float* __restrict__ ha2) {
  __shared__ float xs[16][256];
  __shared__ float redA[16][2], redB[16][2];
  const int t = threadIdx.x;
  const int i0 = blockIdx.x * 16;
  #pragma unroll
  for (int ii = 0; ii < 16; ++ii)
    xs[ii][t & 255] = x[(long long)(i0 + ii) * FI + t];
  __syncthreads();
  const int rg = t >> 7;
  const int f = t & 127;
  float accs[8] = {0.f, 0.f, 0.f, 0.f, 0.f, 0.f, 0.f, 0.f};
  for (int k = 0; k < 256; ++k) {
    const float wv = W[k * FO + f];
    #pragma unroll
    for (int rr = 0; rr < 8; ++rr) accs[rr] = fmaf(xs[rg * 8 + rr][k], wv, accs[rr]);
  }
  {
    ushort4 s0, s1;
    s0.x = f2bf(accs[0]); s0.y = f2bf(accs[1]); s0.z = f2bf(accs[2]); s0.w = f2bf(accs[3]);
    s1.x = f2bf(accs[4]); s1.y = f2bf(accs[5]); s1.z = f2bf(accs[6]); s1.w = f2bf(accs[7]);
    unsigned short* dst = h_t + (long long)f * N + i0 + rg * 8;
    *(ushort4*)dst = s0;
    *(ushort4*)(dst + 4) = s1;
  }
  const float a1f = a[f];
  const float a2f = a[FO + f];
  const int lane = t & 63;
  const int wig = (t >> 6) & 1;
  #pragma unroll
  for (int rr = 0; rr < 8; ++rr) {
    float v1 = accs[rr] * a1f;
    float v2 = accs[rr] * a2f;
    #pragma unroll
    for (int off = 32; off; off >>= 1) { v1 += __shfl_xor(v1, off); v2 += __shfl_xor(v2, off); }
    if (lane == 0) { redA[rg * 8 + rr][wig] = v1; redB[rg * 8 + rr][wig] = v2; }
  }
  __syncthreads();
  if (t < 16) {
    ha1[i0 + t] = redA[t][0] + redA[t][1];
    ha2[i0 + t] = redB[t][0] + redB[t][1];
  }
}

// Kernel B: one wave per row, TWO-PHASE (lrelu monotone => m = lrelu(ei + max_masked ha2)).
// Phase 1: stream adj once -> per-lane bit regs + ballot masks (ws) + masked max (no exp).
// Phase 2: independent exps from LDS-staged ha2 -> s. Writes lse = m + log(s).
template <int WM>
__global__ __launch_bounds__(256) void k_mask(
    const int* __restrict__ adj, const float* __restrict__ ha1g, const float* __restrict__ ha2g,
    u64* __restrict__ msk, float* __restrict__ lse_row) {
  __shared__ float h2s[N];
  const int t = threadIdx.x;
  const int lane = t & 63;
  #pragma unroll
  for (int i = 0; i < 8; ++i) {
    const int idx = i * 1024 + t * 4;
    *(float4*)&h2s[idx] = *(const float4*)(ha2g + idx);
  }
  __syncthreads();
  const int row = blockIdx.x * 4 + (t >> 6);
  const float ei = ha1g[row];
  const int* __restrict__ arow = adj + (size_t)row * N;
  u64* __restrict__ mrow = msk + (size_t)row * 128;
  unsigned int bits0 = 0, bits1 = 0, bits2 = 0, bits3 = 0;
  float mloc = -3.0e38f;
  for (int it = 0; it < 32; ++it) {
    const int j0 = it * 256 + lane * 4;
    const int4 a4 = *(const int4*)(arow + j0);
    const float4 h2 = *(const float4*)&h2s[j0];
    const bool b0 = a4.x > 0, b1 = a4.y > 0, b2 = a4.z > 0, b3 = a4.w > 0;
    bits0 |= (b0 ? 1u : 0u) << it;
    bits1 |= (b1 ? 1u : 0u) << it;
    bits2 |= (b2 ? 1u : 0u) << it;
    bits3 |= (b3 ? 1u : 0u) << it;
    mloc = fmaxf(mloc, b0 ? h2.x : -3.0e38f);
    mloc = fmaxf(mloc, b1 ? h2.y : -3.0e38f);
    mloc = fmaxf(mloc, b2 ? h2.z : -3.0e38f);
    mloc = fmaxf(mloc, b3 ? h2.w : -3.0e38f);
    if (WM) {
      const u64 q0 = __ballot(b0), q1 = __ballot(b1);
      const u64 q2 = __ballot(b2), q3 = __ballot(b3);
      if (lane == 0) {
        u64x2 v01 = {q0, q1}, v23 = {q2, q3};
        *(u64x2*)(mrow + it * 4) = v01;
        *(u64x2*)(mrow + it * 4 + 2) = v23;
      }
    }
  }
  #pragma unroll
  for (int off = 32; off; off >>= 1) mloc = fmaxf(mloc, __shfl_xor(mloc, off));
  const float m = lrelu(ei + mloc);
  float s0 = 0.f, s1 = 0.f, s2 = 0.f, s3 = 0.f;
  for (int it = 0; it < 32; ++it) {
    const int j0 = it * 256 + lane * 4;
    const float4 h2 = *(const float4*)&h2s[j0];
    s0 += ((bits0 >> it) & 1) ? __expf(lrelu(ei + h2.x) - m) : 0.f;
    s1 += ((bits1 >> it) & 1) ? __expf(lrelu(ei + h2.y) - m) : 0.f;
    s2 += ((bits2 >> it) & 1) ? __expf(lrelu(ei + h2.z) - m) : 0.f;
    s3 += ((bits3 >> it) & 1) ? __expf(lrelu(ei + h2.w) - m) : 0.f;
  }
  float s = (s0 + s1) + (s2 + s3);
  #pragma unroll
  for (int off = 32; off; off >>= 1) s += __shfl_xor(s, off);
  if (lane == 0) lse_row[row] = (s > 0.f) ? (m + __logf(s)) : 3.0e38f;
}

// Kernel C: 16 rows/block, 8 waves. Per 128-j tile: compute p (exp from mask+ha2+lse),
// nontemporal f32 attn store, p->bf16 LDS (double-buffered, ONE lgkm-only barrier/iter);
// B-operand (h_t) loads straight global(L2)->VGPR, register double-buffered. mfma PV.
template <int UA>
__global__ __launch_bounds__(512) void k_pv(
    const int* __restrict__ adj, const u64* __restrict__ msk,
    const unsigned short* __restrict__ h_t, const float* __restrict__ ha1g,
    const float* __restrict__ ha2g, const float* __restrict__ lse_row,
    float* __restrict__ h1, float* __restrict__ attn) {
  __shared__ unsigned short p_lds[2][16][136];
  const int t = threadIdx.x;
  const int lane = t & 63;
  const int w = t >> 6;
  const int base = blockIdx.x * 16;
  const int pr = t >> 5;           // p-compute row 0..15
  const int pjw = t & 31;          // 4 consecutive j per thread
  const float ei = ha1g[base + pr];
  const float nls = lse_row[base + pr];
  const u64* __restrict__ mrow = msk + (size_t)(base + pr) * 128;
  const int* __restrict__ arow = adj + (size_t)(base + pr) * N;
  float* __restrict__ atrow = attn + (size_t)(base + pr) * N;

  const int f0 = w * 16;
  const unsigned short* __restrict__ hbase =
      h_t + (size_t)(f0 + (lane & 15)) * N + (lane >> 4) * 8;
  // A-fragment base: row (lane&15), k-offset (lane>>4)*8 — row term included HERE ONLY.
  const unsigned short* pfrag0 = &p_lds[0][lane & 15][(lane >> 4) * 8];

  f32x4 acc = {0.f, 0.f, 0.f, 0.f};

  auto compute_p = [&](int jt) {
    const int j = jt * 128 + pjw * 4;
    bool b0, b1, b2, b3;
    if constexpr (UA) {
      const int4 a4 = *(const int4*)(arow + j);
      b0 = a4.x > 0; b1 = a4.y > 0; b2 = a4.z > 0; b3 = a4.w > 0;
    } else {
      const int it = j >> 8;
      const int l = (j >> 2) & 63;
      const u64x2 qa = *(const u64x2*)(mrow + it * 4);
      const u64x2 qb = *(const u64x2*)(mrow + it * 4 + 2);
      b0 = (qa.x >> l) & 1; b1 = (qa.y >> l) & 1;
      b2 = (qb.x >> l) & 1; b3 = (qb.y >> l) & 1;
    }
    const float4 h2 = *(const float4*)(ha2g + j);
    const float p0 = b0 ? __expf(lrelu(ei + h2.x) - nls) : 0.f;
    const float p1 = b1 ? __expf(lrelu(ei + h2.y) - nls) : 0.f;
    const float p2 = b2 ? __expf(lrelu(ei + h2.z) - nls) : 0.f;
    const float p3 = b3 ? __expf(lrelu(ei + h2.w) - nls) : 0.f;
    f32x4 pv = {p0, p1, p2, p3};
    __builtin_nontemporal_store(pv, (f32x4*)(atrow + j));
    u16x4 pb = {f2bf(p0), f2bf(p1), f2bf(p2), f2bf(p3)};
    *(u16x4*)&p_lds[(jt & 1)][pr][pjw * 4] = pb;
  };

  bf16x8 hA[4], hB[4];
  compute_p(0);
  #pragma unroll
  for (int ks = 0; ks < 4; ++ks) hA[ks] = *(const bf16x8*)(hbase + ks * 32);
  barrier_lds();

  for (int jt = 0; jt < 64; ++jt) {
    if (jt < 63) {
      compute_p(jt + 1);
      #pragma unroll
      for (int ks = 0; ks < 4; ++ks)
        hB[ks] = *(const bf16x8*)(hbase + (jt + 1) * 128 + ks * 32);
    }
    const unsigned short* pf = pfrag0 + (jt & 1) * (16 * 136);
    #pragma unroll
    for (int ks = 0; ks < 4; ++ks) {
      const bf16x8 av = *(const bf16x8*)(pf + ks * 32);
      acc = __builtin_amdgcn_mfma_f32_16x16x32_bf16(av, hA[ks], acc, 0, 0, 0);
    }
    if (jt < 63) {
      barrier_lds();
      #pragma unroll
      for (int ks = 0; ks < 4; ++ks) hA[ks] = hB[ks];
    }
  }
  { // epilogue: D[row=(l>>4)*4+reg][col=l&15], elu
    const int rbase = (lane >> 4) * 4;
    const int col = lane & 15;
    #pragma unroll
    for (int rgi = 0; rgi < 4; ++rgi) {
      float v = acc[rgi];
      v = v > 0.f ? v : __expf(v) - 1.f;
      h1[(long long)(base + rbase + rgi) * FO + f0 + col] = v;
    }
  }
}

extern "C" void kernel_launch(void* const* d_in, const int* in_sizes, int n_in,
                              void* d_out, int out_size, void* d_ws, size_t ws_size,
                              hipStream_t stream) {
  const float* x = (const float*)d_in[0];
  const int* adj = (const int*)d_in[1];
  const float* W = (const float*)d_in[2];
  const float* a = (const float*)d_in[3];
  float* h1 = (float*)d_out;
  float* attn = (float*)d_out + (size_t)N * FO;

  char* wsb = (char*)d_ws;
  unsigned short* h_t = (unsigned short*)wsb;                       // 2 MB
  float* ha1 = (float*)(wsb + (size_t)FO * N * 2);                  // 32 KB
  float* ha2 = ha1 + N;                                             // 32 KB
  float* lse = ha2 + N;                                             // 32 KB
  const size_t msk_off = (size_t)FO * N * 2 + 3 * (size_t)N * 4;    // 2,195,456
  u64* msk = (u64*)(wsb + msk_off);                                 // 8 MB
  const size_t need = msk_off + (size_t)N * 128 * 8;

  k_prep<<<N / 16, 256, 0, stream>>>(x, W, a, h_t, ha1, ha2);
  if (ws_size >= need) {
    k_mask<1><<<N / 4, 256, 0, stream>>>(adj, ha1, ha2, msk, lse);
    k_pv<0><<<N / 16, 512, 0, stream>>>(adj, msk, h_t, ha1, ha2, lse, h1, attn);
  } else {
    k_mask<0><<<N / 4, 256, 0, stream>>>(adj, ha1, ha2, msk, lse);
    k_pv<1><<<N / 16, 512, 0, stream>>>(adj, msk, h_t, ha1, ha2, lse, h1, attn);
  }
}